// Round 2
// baseline (398.830 us; speedup 1.0000x reference)
//
#include <hip/hip_runtime.h>

// Problem constants (from setup_inputs): b=4, h=128, w=512, c=128, num_splits=8
#define BH      512   // b*h
#define W_ROWS  512   // w
#define C_DIM   128   // c
#define NSPLIT  8
#define WIN     64
#define SHIFT   32    // win/2
#define NW      8     // windows processed per block (same split, consecutive bh)

typedef __attribute__((ext_vector_type(8))) short  short8;
typedef __attribute__((ext_vector_type(4))) float  floatx4;

__device__ __forceinline__ ushort f2bf(float x) {
    union { float f; unsigned u; } c; c.f = x;
    unsigned u = c.u;
    return (ushort)((u + 0x7FFFu + ((u >> 16) & 1u)) >> 16);  // RNE
}

// Persistent block: one (split s, bh-octet) per block, NW=8 windows pipelined.
// Rationale (r1 post-mortem): kernel is latency-chain bound, not BW/occupancy
// bound (L3-warm dispatch ran at identical dur). So: prefetch next window's
// K/V/Q into registers while computing the current window; hoist the
// window-invariant mask tile + rolled-row offsets out of the loop; drop the
// softmax barriers (PV reads only its own wave's sP rows -> wave-local LDS
// ordering via lgkmcnt suffices). Steady state: 2 barriers/window, ~24 KB/wave
// of global loads in flight under QK^T/softmax/PV.
// LDS 45056 B; grid 512 -> 2 blocks/CU; VGPR budget 256 via launch_bounds(,2).
__global__ __launch_bounds__(256, 2)
void swin_attn_kernel(const float* __restrict__ qg,
                      const float* __restrict__ kg,
                      const float* __restrict__ vg,
                      const float* __restrict__ mg,
                      float* __restrict__ og)
{
    __shared__ __align__(16) ushort sK[64][136];     // 17408 B, 272B row stride
    __shared__ __align__(16) char   sVt[128 * 144];  // 18432 B, 16B-chunk XOR swizzle
    __shared__ __align__(16) ushort sP[64][72];      //  9216 B, wave-private rows

    const int tid  = threadIdx.x;
    const int s    = blockIdx.x & 7;
    const int bh0  = (blockIdx.x >> 3) * NW;
    const int wv   = tid >> 6;     // wave 0..3
    const int lane = tid & 63;
    const int l16  = lane & 15;
    const int quad = lane >> 4;

    // staging map: each thread owns 8 consecutive key rows x 4 channels
    const int j  = tid & 31;
    const int h  = tid >> 5;
    const int c0 = j * 4;
    const int r0 = h * 8;

    // ---- window-invariant precompute (s fixed per block) ----
    int kvoff[8];                                    // rolled K/V row offsets (floats)
    #pragma unroll
    for (int i = 0; i < 8; ++i)
        kvoff[i] = ((s * WIN + r0 + i + SHIFT) & (W_ROWS - 1)) * C_DIM + c0;

    const int qrow = wv * 16 + l16;
    const int qoff = ((s * WIN + qrow + SHIFT) & (W_ROWS - 1)) * C_DIM + quad * 8;

    int ooff[4];
    #pragma unroll
    for (int r = 0; r < 4; ++r) {
        const int qw = wv * 16 + quad * 4 + r;
        ooff[r] = ((s * WIN + qw + SHIFT) & (W_ROWS - 1)) * C_DIM + l16;
    }

    // mask tile for this split: 16 floats/thread, loaded ONCE, reused NW times
    float mk[4][4];                                  // [r][t]
    {
        const float* mrow = mg + s * (WIN * WIN);
        #pragma unroll
        for (int r = 0; r < 4; ++r) {
            const int qw = wv * 16 + quad * 4 + r;
            #pragma unroll
            for (int t = 0; t < 4; ++t)
                mk[r][t] = mrow[qw * WIN + t * 16 + l16];
        }
    }

    floatx4 kr[8], vr[8], qa[4], qb[4];              // prefetch registers
    short8  qf[4];                                   // Q bf16 fragments (carried)
    const floatx4 fz = {0.f, 0.f, 0.f, 0.f};

    // convert prefetch regs -> LDS (K row-major, V transposed+swizzled) + build qf
    auto stage_write = [&]() {
        #pragma unroll
        for (int i = 0; i < 8; ++i) {
            ushort4 kb;
            kb.x = f2bf(kr[i][0]); kb.y = f2bf(kr[i][1]);
            kb.z = f2bf(kr[i][2]); kb.w = f2bf(kr[i][3]);
            *(ushort4*)&sK[r0 + i][c0] = kb;
        }
        #pragma unroll
        for (int m = 0; m < 4; ++m) {
            short8 col;
            #pragma unroll
            for (int i = 0; i < 8; ++i) col[i] = (short)f2bf(vr[i][m]);
            const int chnk = h ^ (j & 7);            // (ch>>2)&7, ch = c0+m
            *(short8*)(sVt + (size_t)(c0 + m) * 144 + chnk * 16) = col;
        }
        #pragma unroll
        for (int kk = 0; kk < 4; ++kk) {
            short8 f;
            f[0] = (short)f2bf(qa[kk][0]); f[1] = (short)f2bf(qa[kk][1]);
            f[2] = (short)f2bf(qa[kk][2]); f[3] = (short)f2bf(qa[kk][3]);
            f[4] = (short)f2bf(qb[kk][0]); f[5] = (short)f2bf(qb[kk][1]);
            f[6] = (short)f2bf(qb[kk][2]); f[7] = (short)f2bf(qb[kk][3]);
            qf[kk] = f;
        }
    };

    // ---- prologue: load + stage window 0 ----
    {
        const size_t base = (size_t)bh0 * (W_ROWS * C_DIM);
        #pragma unroll
        for (int i = 0; i < 8; ++i) kr[i] = *(const floatx4*)(kg + base + kvoff[i]);
        #pragma unroll
        for (int i = 0; i < 8; ++i) vr[i] = *(const floatx4*)(vg + base + kvoff[i]);
        #pragma unroll
        for (int kk = 0; kk < 4; ++kk) {
            qa[kk] = *(const floatx4*)(qg + base + qoff + kk * 32);
            qb[kk] = *(const floatx4*)(qg + base + qoff + kk * 32 + 4);
        }
    }
    stage_write();
    __syncthreads();

    for (int w = 0; w < NW; ++w) {
        // ---- issue next window's loads; they fly under this window's compute ----
        if (w + 1 < NW) {
            const size_t basen = (size_t)(bh0 + w + 1) * (W_ROWS * C_DIM);
            #pragma unroll
            for (int i = 0; i < 8; ++i) kr[i] = *(const floatx4*)(kg + basen + kvoff[i]);
            #pragma unroll
            for (int i = 0; i < 8; ++i) vr[i] = *(const floatx4*)(vg + basen + kvoff[i]);
            #pragma unroll
            for (int kk = 0; kk < 4; ++kk) {
                qa[kk] = *(const floatx4*)(qg + basen + qoff + kk * 32);
                qb[kk] = *(const floatx4*)(qg + basen + qoff + kk * 32 + 4);
            }
        }

        // ---- QK^T: per-wave 16x64 strip ----
        floatx4 acc[4];
        #pragma unroll
        for (int t = 0; t < 4; ++t) acc[t] = fz;
        #pragma unroll
        for (int kk = 0; kk < 4; ++kk) {
            const int ch0 = kk * 32 + quad * 8;
            #pragma unroll
            for (int t = 0; t < 4; ++t) {
                short8 bf = *(const short8*)&sK[t * 16 + l16][ch0];
                acc[t] = __builtin_amdgcn_mfma_f32_16x16x32_bf16(qf[kk], bf, acc[t], 0, 0, 0);
            }
        }

        // ---- scale + mask + softmax (registers) ----
        float pr[4][4];                              // [t][r]
        #pragma unroll
        for (int r = 0; r < 4; ++r) {
            float mx = -3.0e38f;
            #pragma unroll
            for (int t = 0; t < 4; ++t) {
                float val = acc[t][r] * 0.08838834764831845f + mk[r][t];
                pr[t][r] = val;
                mx = fmaxf(mx, val);
            }
            mx = fmaxf(mx, __shfl_xor(mx, 1));
            mx = fmaxf(mx, __shfl_xor(mx, 2));
            mx = fmaxf(mx, __shfl_xor(mx, 4));
            mx = fmaxf(mx, __shfl_xor(mx, 8));
            float sum = 0.f;
            #pragma unroll
            for (int t = 0; t < 4; ++t) {
                float e = __expf(pr[t][r] - mx);
                pr[t][r] = e;
                sum += e;
            }
            sum += __shfl_xor(sum, 1);
            sum += __shfl_xor(sum, 2);
            sum += __shfl_xor(sum, 4);
            sum += __shfl_xor(sum, 8);
            float rs = 1.0f / sum;
            #pragma unroll
            for (int t = 0; t < 4; ++t) pr[t][r] *= rs;
        }

        // ---- P -> sP: wave-private rows, NO barrier needed (lgkmcnt orders it) ----
        #pragma unroll
        for (int r = 0; r < 4; ++r) {
            const int qw = wv * 16 + quad * 4 + r;
            #pragma unroll
            for (int t = 0; t < 4; ++t)
                sP[qw][t * 16 + l16] = f2bf(pr[t][r]);
        }

        // ---- PV: out[q][ch] ----
        floatx4 o[8];
        #pragma unroll
        for (int t = 0; t < 8; ++t) o[t] = fz;
        #pragma unroll
        for (int kk = 0; kk < 2; ++kk) {
            short8 pf = *(const short8*)&sP[wv * 16 + l16][kk * 32 + quad * 8];
            #pragma unroll
            for (int t = 0; t < 8; ++t) {
                const int ch   = t * 16 + l16;
                const int chnk = (kk * 4 + quad) ^ ((ch >> 2) & 7);
                short8 vf = *(const short8*)(sVt + (size_t)ch * 144 + chnk * 16);
                o[t] = __builtin_amdgcn_mfma_f32_16x16x32_bf16(pf, vf, o[t], 0, 0, 0);
            }
        }

        // ---- epilogue: fp32 store with inverse roll ----
        {
            const size_t baseo = (size_t)(bh0 + w) * (W_ROWS * C_DIM);
            #pragma unroll
            for (int r = 0; r < 4; ++r) {
                float* op = og + baseo + ooff[r];
                #pragma unroll
                for (int t = 0; t < 8; ++t)
                    op[t * 16] = o[t][r];
            }
        }

        __syncthreads();                  // A: all waves done reading sK/sVt
        if (w + 1 < NW) stage_write();    // overwrite LDS with next window
        __syncthreads();                  // B: LDS ready for next QK^T
    }
}

extern "C" void kernel_launch(void* const* d_in, const int* in_sizes, int n_in,
                              void* d_out, int out_size, void* d_ws, size_t ws_size,
                              hipStream_t stream) {
    const float* q = (const float*)d_in[0];
    const float* k = (const float*)d_in[1];
    const float* v = (const float*)d_in[2];
    const float* m = (const float*)d_in[3];
    float* out = (float*)d_out;
    dim3 grid(BH * NSPLIT / NW), block(256);
    hipLaunchKernelGGL(swin_attn_kernel, grid, block, 0, stream, q, k, v, m, out);
}